// Round 8
// baseline (179.830 us; speedup 1.0000x reference)
//
#include <hip/hip_runtime.h>

// out[p][f] = sum_s x[p][s] * K[s][f];  P = 393,216, K 64x64 fp32.
//
// R12: R11 (load-first, 3 tiles) nulled because each short-lived wave pays a
// mandatory terminal s_waitcnt vmcnt(0) (store drain) -- CU slots held idle,
// serialized 8 blocks deep. R9 (persistent, 12 tiles) nulled because its
// rolling issue order made every in-loop load-wait drain older stores. Each
// fix was nullified by the other's absence. R12 = both halves + zero
// barriers:
//   * K B-frags built per-lane DIRECTLY from global (16KB, L2-hot; no LDS
//     staging, no __syncthreads in the entire kernel).
//   * 4 tiles/wave; all 16 dwordx4 loads issued in ONE pinned burst, in
//     frag layout (R6-verified: no FETCH amplification). Queue = [16 loads]
//     [stores...]; per-tile wait is CONSTANT vmcnt(12) -> no load-wait ever
//     retires a store.
//   * 1536 blocks, VGPR ~180, LDS 17.4KB -> 2 blocks/CU co-resident: block
//     A's terminal drain overlaps block B's work; drain amortized 16KB at
//     a time.
//   * store path = R8b-verified LDS transpose -> contiguous nt dwordx4
//     (WRITE=98MB clean).
// Numerics unchanged (3-term bf16 hi/lo, absmax 0.03125).
// Prediction: dur 59.5 -> 30-42us, hbm >=3.8 TB/s, FETCH ~49MB, WRITE
// ~98MB. PRE-COMMIT: null (~60us) => 8 concordant nulls, declare ROOFLINE.

#define THREADS 256
#define WPB     4
#define NT      4           // tiles/wave; 1536 blk * 4 * 4 = 24576 exact
#define OROW    68          // transpose scratch row stride (floats)

typedef __attribute__((ext_vector_type(8))) short bf16x8;
typedef __attribute__((ext_vector_type(4))) float f32x4;

static __device__ __forceinline__ unsigned short bf16_rne(float f) {
    unsigned int u = __float_as_uint(f);
    u += 0x7fffu + ((u >> 16) & 1u);
    return (unsigned short)(u >> 16);
}
static __device__ __forceinline__ float bf16f(unsigned short h) {
    return __uint_as_float((unsigned int)h << 16);
}

__global__ __launch_bounds__(THREADS)
void dct_kernel(const float* __restrict__ x,
                const float* __restrict__ Kmat,
                float* __restrict__ out) {
    __shared__ __align__(16) float oscr[WPB][16][OROW];   // 17.4 KB, wave-private

    const int tid  = threadIdx.x;
    const int lane = tid & 63;
    const int wv   = tid >> 6;
    const int l15  = lane & 15;
    const int quad = lane >> 4;

    const int totw = (int)gridDim.x * WPB;              // 6144 waves
    const long long wt0 = (long long)blockIdx.x * WPB + wv;
    const float* src = x + (wt0 * 16 + l15) * 64 + quad * 8;   // frag-layout base
    float* dst = out + wt0 * 1024;
    const long long SSTEP = (long long)totw * 1024;     // float step per s

    // ---- K B-frags: per-lane direct global loads (L2-hot 16KB), no LDS ----
    // combo = kc*4+ft ; lane holds B[k = kc*32+quad*8+j][n = ft*16+l15]
    bf16x8 Bh[8], Bl[8];
#pragma unroll
    for (int combo = 0; combo < 8; ++combo) {
        const int kc = combo >> 2, ft = combo & 3;
        short hh[8], ll[8];
#pragma unroll
        for (int j = 0; j < 8; ++j) {
            float v = Kmat[(kc * 32 + quad * 8 + j) * 64 + ft * 16 + l15];
            unsigned short h = bf16_rne(v);
            hh[j] = (short)h;
            ll[j] = (short)bf16_rne(v - bf16f(h));
        }
        Bh[combo] = *(bf16x8*)hh;
        Bl[combo] = *(bf16x8*)ll;
    }
    // K loads fully consumed above (compiler waits emitted); pin the boundary
    __builtin_amdgcn_sched_barrier(0);

    // ---- LOAD-FIRST BURST: all 4 tiles, 16x dwordx4, frag layout ----
    // per tile: lane (quad,l15) loads x[p=l15][quad*8..+8] and [32+quad*8..+8]
    f32x4 cc[NT][4];
#pragma unroll
    for (int t = 0; t < NT; ++t) {
        const float* ts = src + (long long)t * SSTEP;
        cc[t][0] = *(const f32x4*)(ts);
        cc[t][1] = *(const f32x4*)(ts + 4);
        cc[t][2] = *(const f32x4*)(ts + 32);
        cc[t][3] = *(const f32x4*)(ts + 36);
    }
    // pin: no store may be hoisted above this point, no load sunk below
    __builtin_amdgcn_sched_barrier(0);

    // ---- 4 unrolled tiles; ALL loads older than ALL stores ----
#pragma unroll
    for (int s = 0; s < NT; ++s) {
        // tile s's 4 loads are ops 4s+1..4s+4 of the 16-load burst; issued
        // since then: (12-4s) loads + 4s stores = 12. Constant counted wait;
        // never forces a store to retire.
        asm volatile("s_waitcnt vmcnt(12)" ::: "memory");
        __builtin_amdgcn_sched_barrier(0);

        // convert to bf16 hi/lo A-frags (registers are already frag-layout)
        bf16x8 Ahi[2], Alo[2];
#pragma unroll
        for (int kc = 0; kc < 2; ++kc) {
            float av[8];
            *(f32x4*)&av[0] = cc[s][kc * 2];
            *(f32x4*)&av[4] = cc[s][kc * 2 + 1];
            short ah[8], al[8];
#pragma unroll
            for (int j = 0; j < 8; ++j) {
                unsigned short h = bf16_rne(av[j]);
                ah[j] = (short)h;
                al[j] = (short)bf16_rne(av[j] - bf16f(h));
            }
            Ahi[kc] = *(bf16x8*)ah;
            Alo[kc] = *(bf16x8*)al;
        }

        f32x4 acc[4];
#pragma unroll
        for (int t = 0; t < 4; ++t) acc[t] = (f32x4){0.f, 0.f, 0.f, 0.f};
#pragma unroll
        for (int kc = 0; kc < 2; ++kc)
#pragma unroll
            for (int ft = 0; ft < 4; ++ft) {
                const int c = kc * 4 + ft;
                acc[ft] = __builtin_amdgcn_mfma_f32_16x16x32_bf16(Ahi[kc], Bh[c], acc[ft], 0, 0, 0);
                acc[ft] = __builtin_amdgcn_mfma_f32_16x16x32_bf16(Alo[kc], Bh[c], acc[ft], 0, 0, 0);
                acc[ft] = __builtin_amdgcn_mfma_f32_16x16x32_bf16(Ahi[kc], Bl[c], acc[ft], 0, 0, 0);
            }

        // epilogue: wave-private LDS transpose (no barrier; same-wave DS is
        // in-order) -> 4x contiguous nt dwordx4 (1KB fully-covered / instr)
#pragma unroll
        for (int ft = 0; ft < 4; ++ft)
#pragma unroll
            for (int r = 0; r < 4; ++r)
                oscr[wv][quad * 4 + r][ft * 16 + l15] = acc[ft][r];
        float* ob = dst + (long long)s * SSTEP;
#pragma unroll
        for (int i = 0; i < 4; ++i) {
            f32x4 v = *(const f32x4*)&oscr[wv][i * 4 + quad][l15 * 4];
            __builtin_nontemporal_store(v, (f32x4*)(ob + i * 256 + lane * 4));
        }
    }
    // terminal vmcnt(0) store drain: paid once per 16KB of stores, and
    // overlapped with the co-resident block's loads/compute (2 blk/CU).
}

extern "C" void kernel_launch(void* const* d_in, const int* in_sizes, int n_in,
                              void* d_out, int out_size, void* d_ws, size_t ws_size,
                              hipStream_t stream) {
    const float* x = (const float*)d_in[0];   // (8,3,1024,1024) fp32
    const float* K = (const float*)d_in[1];   // (64,64) fp32
    float* out = (float*)d_out;

    const int total = in_sizes[0];            // 25,165,824 floats
    const int num_patches = total / 64;       // 393,216
    const int wave_tiles  = num_patches / 16; // 24,576
    const int blocks = wave_tiles / (WPB * NT);  // 1536, exact

    dct_kernel<<<blocks, THREADS, 0, stream>>>(x, K, out);
}